// Round 3
// baseline (902.576 us; speedup 1.0000x reference)
//
#include <hip/hip_runtime.h>

// Fused attention: scores = x1 @ x2^T, softmax(k), inverted dropout (mask on
// numerator only; denominator over ALL k), out = attn @ x2.
// Baseline: fp32 SIMT flash-style. B=32 Q=512 K=511 D=768.
// NOTE: drop_mask assumed int32 (harness doc: "integer -> const int*").

namespace {

constexpr int NB = 32;
constexpr int NQ = 512;
constexpr int NK = 511;
constexpr int ND = 768;
constexpr int TQ = 32;    // q rows per workgroup
constexpr int TK = 64;    // k per tile
constexpr int DC = 128;   // d chunk staged in LDS
constexpr int NTH = 512;  // 8 waves
constexpr int APITCH = DC + 4;  // +4 floats: breaks stride-128 bank conflicts, keeps 16B align
constexpr int BPITCH = DC + 4;
constexpr int SPITCH = TQ + 1;  // score tile stored transposed [k][q], pitch 33
constexpr int NKT = (NK + TK - 1) / TK;  // 8
constexpr float INV_KEEP = 1.0f / 0.9f;

__global__ __launch_bounds__(NTH, 2)
void fused_attn(const float* __restrict__ x1,
                const float* __restrict__ x2,
                const int* __restrict__ dmask,
                float* __restrict__ out)
{
    __shared__ float Ab[TQ * APITCH];   // x1 tile chunk   16.5 KB
    __shared__ float Bb[TK * BPITCH];   // x2 tile chunk   33 KB
    __shared__ float Sb[TK * SPITCH];   // scores/P, [k][q] 8.25 KB

    const int t  = threadIdx.x;
    const int b  = blockIdx.x >> 4;          // 16 q-tiles per batch
    const int q0 = (blockIdx.x & 15) * TQ;

    // ownership mapping for O/softmax: thread -> (q row, 16-lane d/k slice)
    const int qo  = t >> 4;   // 0..31
    const int l16 = t & 15;   // 0..15
    // mapping for score phase: 2q x 2k micro-tile per thread
    const int qp  = t & 15;   // q-pair index
    const int kp  = t >> 4;   // k-pair index 0..31

    const float* x1b = x1 + ((size_t)(b * NQ + q0)) * ND;
    const float* x2b = x2 + ((size_t)b * NK) * ND;
    const int*   mb  = dmask + ((size_t)(b * NQ + q0)) * NK;

    // O accumulator: q=qo, d = l16*4 + 64*j + i
    float o[12][4];
    #pragma unroll
    for (int j = 0; j < 12; ++j)
        #pragma unroll
        for (int i = 0; i < 4; ++i) o[j][i] = 0.f;

    float m_run = -3.0e38f;   // running max (over ALL k, unmasked)
    float l_run = 0.f;        // running sum of exp (unmasked)

    for (int kt = 0; kt < NKT; ++kt) {
        const int k0 = kt * TK;

        // ---------------- score phase: S[TQ][TK] over D in DC chunks --------
        float s00 = 0.f, s01 = 0.f, s10 = 0.f, s11 = 0.f;

        for (int dc = 0; dc < ND; dc += DC) {
            __syncthreads();   // prior readers of Ab/Bb done
            #pragma unroll
            for (int r = 0; r < (TQ * DC / 4) / NTH; ++r) {   // 2
                int idx = t + NTH * r;
                int row = idx >> 5;            // 32 float4 per row
                int c   = (idx & 31) << 2;
                float4 v = *(const float4*)(x1b + row * ND + dc + c);
                *(float4*)(&Ab[row * APITCH + c]) = v;
            }
            #pragma unroll
            for (int r = 0; r < (TK * DC / 4) / NTH; ++r) {   // 4
                int idx = t + NTH * r;
                int row = idx >> 5;
                int c   = (idx & 31) << 2;
                float4 v = make_float4(0.f, 0.f, 0.f, 0.f);
                if (k0 + row < NK)
                    v = *(const float4*)(x2b + (size_t)(k0 + row) * ND + dc + c);
                *(float4*)(&Bb[row * BPITCH + c]) = v;
            }
            __syncthreads();

            const float* pa0 = &Ab[(2 * qp)     * APITCH];
            const float* pa1 = &Ab[(2 * qp + 1) * APITCH];
            const float* pb0 = &Bb[(2 * kp)     * BPITCH];
            const float* pb1 = &Bb[(2 * kp + 1) * BPITCH];
            #pragma unroll 8
            for (int d = 0; d < DC; d += 4) {
                float4 a0 = *(const float4*)(pa0 + d);
                float4 a1 = *(const float4*)(pa1 + d);
                float4 b0 = *(const float4*)(pb0 + d);
                float4 b1 = *(const float4*)(pb1 + d);
                s00 = fmaf(a0.x, b0.x, s00); s00 = fmaf(a0.y, b0.y, s00);
                s00 = fmaf(a0.z, b0.z, s00); s00 = fmaf(a0.w, b0.w, s00);
                s01 = fmaf(a0.x, b1.x, s01); s01 = fmaf(a0.y, b1.y, s01);
                s01 = fmaf(a0.z, b1.z, s01); s01 = fmaf(a0.w, b1.w, s01);
                s10 = fmaf(a1.x, b0.x, s10); s10 = fmaf(a1.y, b0.y, s10);
                s10 = fmaf(a1.z, b0.z, s10); s10 = fmaf(a1.w, b0.w, s10);
                s11 = fmaf(a1.x, b1.x, s11); s11 = fmaf(a1.y, b1.y, s11);
                s11 = fmaf(a1.z, b1.z, s11); s11 = fmaf(a1.w, b1.w, s11);
            }
        }

        // invalidate k >= NK (last tile)
        if (k0 + 2 * kp     >= NK) { s00 = -3.0e38f; s10 = -3.0e38f; }
        if (k0 + 2 * kp + 1 >= NK) { s01 = -3.0e38f; s11 = -3.0e38f; }

        // store scores transposed [k][q] (prior Sb readers separated by the
        // dc-loop barriers above)
        Sb[(2 * kp)     * SPITCH + 2 * qp]     = s00;
        Sb[(2 * kp + 1) * SPITCH + 2 * qp]     = s01;
        Sb[(2 * kp)     * SPITCH + 2 * qp + 1] = s10;
        Sb[(2 * kp + 1) * SPITCH + 2 * qp + 1] = s11;
        __syncthreads();

        // ---------------- online softmax: thread (qo, l16) owns 4 k-slots ---
        float sv[4], e[4];
        float tm = -3.0e38f;
        #pragma unroll
        for (int i = 0; i < 4; ++i) {
            sv[i] = Sb[(l16 * 4 + i) * SPITCH + qo];
            tm = fmaxf(tm, sv[i]);
        }
        #pragma unroll
        for (int d = 1; d < 16; d <<= 1) tm = fmaxf(tm, __shfl_xor(tm, d));
        const float m_new = fmaxf(m_run, tm);
        const float fac = expf(m_run - m_new);
        float rs = 0.f;
        #pragma unroll
        for (int i = 0; i < 4; ++i) { e[i] = expf(sv[i] - m_new); rs += e[i]; }
        #pragma unroll
        for (int d = 1; d < 16; d <<= 1) rs += __shfl_xor(rs, d);
        l_run = l_run * fac + rs;   // denominator over ALL k (mask NOT applied)
        m_run = m_new;
        #pragma unroll
        for (int j = 0; j < 12; ++j)
            #pragma unroll
            for (int i = 0; i < 4; ++i) o[j][i] *= fac;

        // dropout mask applied to numerator only; write P (same slots read)
        #pragma unroll
        for (int i = 0; i < 4; ++i) {
            const int k = k0 + l16 * 4 + i;
            float p = 0.f;
            if (k < NK && mb[(size_t)qo * NK + k] != 0) p = e[i];
            Sb[(l16 * 4 + i) * SPITCH + qo] = p;
        }

        // ---------------- PV phase: O += P @ x2-tile, D in DC chunks --------
        #pragma unroll
        for (int dc = 0; dc < ND; dc += DC) {
            __syncthreads();   // P writes done; prior Bb readers done
            #pragma unroll
            for (int r = 0; r < (TK * DC / 4) / NTH; ++r) {
                int idx = t + NTH * r;
                int row = idx >> 5;
                int c   = (idx & 31) << 2;
                float4 v = make_float4(0.f, 0.f, 0.f, 0.f);
                if (k0 + row < NK)
                    v = *(const float4*)(x2b + (size_t)(k0 + row) * ND + dc + c);
                *(float4*)(&Bb[row * BPITCH + c]) = v;
            }
            __syncthreads();

            const int j0 = dc >> 6;   // compile-time (loop unrolled)
            #pragma unroll 4
            for (int k = 0; k < TK; ++k) {
                const float p = Sb[k * SPITCH + qo];
                const float4 bv0 = *(const float4*)(&Bb[k * BPITCH + l16 * 4]);
                const float4 bv1 = *(const float4*)(&Bb[k * BPITCH + 64 + l16 * 4]);
                o[j0][0]     = fmaf(p, bv0.x, o[j0][0]);
                o[j0][1]     = fmaf(p, bv0.y, o[j0][1]);
                o[j0][2]     = fmaf(p, bv0.z, o[j0][2]);
                o[j0][3]     = fmaf(p, bv0.w, o[j0][3]);
                o[j0 + 1][0] = fmaf(p, bv1.x, o[j0 + 1][0]);
                o[j0 + 1][1] = fmaf(p, bv1.y, o[j0 + 1][1]);
                o[j0 + 1][2] = fmaf(p, bv1.z, o[j0 + 1][2]);
                o[j0 + 1][3] = fmaf(p, bv1.w, o[j0 + 1][3]);
            }
        }
    }

    // ---------------- epilogue ------------------------------------------
    const float scale = INV_KEEP / l_run;
    float* ob = out + ((size_t)(b * NQ + q0 + qo)) * ND;
    #pragma unroll
    for (int j = 0; j < 12; ++j) {
        float4 v;
        v.x = o[j][0] * scale;
        v.y = o[j][1] * scale;
        v.z = o[j][2] * scale;
        v.w = o[j][3] * scale;
        *(float4*)(ob + j * 64 + l16 * 4) = v;
    }
}

}  // namespace

extern "C" void kernel_launch(void* const* d_in, const int* in_sizes, int n_in,
                              void* d_out, int out_size, void* d_ws, size_t ws_size,
                              hipStream_t stream)
{
    const float* x1    = (const float*)d_in[0];
    const float* x2    = (const float*)d_in[1];
    const int*   dmask = (const int*)d_in[2];
    float*       out   = (float*)d_out;

    dim3 grid(NB * (NQ / TQ));   // 512 workgroups
    dim3 block(NTH);
    hipLaunchKernelGGL(fused_attn, grid, block, 0, stream, x1, x2, dmask, out);
}

// Round 4
// 319.162 us; speedup vs baseline: 2.8280x; 2.8280x over previous
//
#include <hip/hip_runtime.h>

// Fused attention, MFMA version.
//   scores = x1 @ x2^T  (bf16 hi/lo split x3 MFMA passes -> ~2e-4 score error)
//   softmax over k (denominator over ALL k; k=511 pad column killed)
//   dropout: numerator *= mask (int32), output scaled by INV_KEEP/l[q]
//   out = P @ x2  (bf16 MFMA, V staged transposed in LDS)
// Geometry: 256 blocks (1/CU), 8 waves, TQ=64 q-rows/block, full K=512 in regs.
// B=32 Q=512 K=511 D=768 fp32 in/out.

namespace {

constexpr int NB = 32, NQ = 512, NK = 511, ND = 768;
constexpr int TQ = 64, NTH = 512;
constexpr float INV_KEEP = 1.0f / 0.9f;

// ---- LDS layout (bytes). Staging region aliases Vt (phases are disjoint).
constexpr int P_PITCH_B = 1040;              // 520 bf16/row: slot=(r+g)%8 -> conflict-free
constexpr int P_BASE    = 0;
constexpr int P_BYTES   = TQ * P_PITCH_B;    // 66560
constexpr int X1H = P_BYTES;                 // 64 rows x 80 B (40 bf16, 32 used)
constexpr int X1L = X1H + 64 * 80;
constexpr int X2H = X1L + 64 * 80;           // 512 rows x 80 B
constexpr int X2L = X2H + 512 * 80;
constexpr int STG_END = X2L + 512 * 80;      // 158720
constexpr int VT  = P_BYTES;                 // 768 rows x 80 B = 61440 (alias)
constexpr int RED = STG_END;                 // 64*8 f32 partials
constexpr int MLD = RED + 2048;              // 64 f32 row max
constexpr int FLD = MLD + 256;               // 64 f32 INV_KEEP/l
constexpr int LDS_TOTAL = FLD + 256;         // 161280 <= 163840

typedef short s8v  __attribute__((ext_vector_type(8)));   // 8 bf16 = 1 MFMA operand
typedef float f32x4 __attribute__((ext_vector_type(4)));  // MFMA accumulator

__device__ __forceinline__ unsigned f2bf_rne(float x) {
    unsigned u = __float_as_uint(x);
    return (u + 0x7FFFu + ((u >> 16) & 1u)) >> 16;
}
// pack two floats -> [bf(a) | bf(b)<<16]
__device__ __forceinline__ unsigned pk_hi(float a, float b) {
    return f2bf_rne(a) | (f2bf_rne(b) << 16);
}
// hi/lo split of two floats -> packed hi word, packed lo word (lo truncated)
__device__ __forceinline__ void split2(float a, float b, unsigned& hi, unsigned& lo) {
    unsigned ha = f2bf_rne(a), hb = f2bf_rne(b);
    float ra = a - __uint_as_float(ha << 16);
    float rb = b - __uint_as_float(hb << 16);
    hi = ha | (hb << 16);
    lo = (__float_as_uint(ra) >> 16) | ((__float_as_uint(rb) >> 16) << 16);
}

__global__ __launch_bounds__(NTH, 2)
void fused_attn(const float* __restrict__ x1, const float* __restrict__ x2,
                const int* __restrict__ dmask, float* __restrict__ out)
{
    extern __shared__ char smem[];
    const int t  = threadIdx.x;
    const int w  = t >> 6;        // wave 0..7  (owns k-slice [64w,64w+64) in QK^T, d-slice [96w,96w+96) in PV)
    const int li = t & 15;        // lane 0..15
    const int g  = (t & 63) >> 4; // quarter 0..3

    const int b  = blockIdx.x >> 3;
    const int q0 = (blockIdx.x & 7) * TQ;

    const float* x1b = x1 + (size_t)(b * NQ + q0) * ND;
    const float* x2b = x2 + (size_t)b * NK * ND;
    const int*   mb  = dmask + (size_t)(b * NQ + q0) * NK;
    float*       ob  = out + (size_t)(b * NQ + q0) * ND;

    float* redp = (float*)(smem + RED);
    float* mldp = (float*)(smem + MLD);
    float* fldp = (float*)(smem + FLD);

    // ================= Phase 1: S[64][512] = x1 @ x2^T (split bf16) =========
    f32x4 acc[4][4] = {};   // [qb][c]: q = qb*16 + g*4 + r, k = 64w + 16c + li

    float4 px1;
    float4 px2[8];
    auto loadC = [&](int dc) {
        const int d0 = dc * 32;
        px1 = *(const float4*)(x1b + (size_t)(t >> 3) * ND + d0 + (t & 7) * 4);
        if (t < NK) {
            #pragma unroll
            for (int j = 0; j < 8; ++j)
                px2[j] = *(const float4*)(x2b + (size_t)t * ND + d0 + j * 4);
        } else {
            #pragma unroll
            for (int j = 0; j < 8; ++j) px2[j] = make_float4(0.f, 0.f, 0.f, 0.f);
        }
    };
    auto writeC = [&]() {
        unsigned h0, l0, h1, l1;
        split2(px1.x, px1.y, h0, l0);
        split2(px1.z, px1.w, h1, l1);
        *(uint2*)(smem + X1H + (t >> 3) * 80 + (t & 7) * 8) = make_uint2(h0, h1);
        *(uint2*)(smem + X1L + (t >> 3) * 80 + (t & 7) * 8) = make_uint2(l0, l1);
        unsigned hh[16], ll[16];
        #pragma unroll
        for (int j = 0; j < 8; ++j) {
            split2(px2[j].x, px2[j].y, hh[2 * j],     ll[2 * j]);
            split2(px2[j].z, px2[j].w, hh[2 * j + 1], ll[2 * j + 1]);
        }
        #pragma unroll
        for (int j = 0; j < 4; ++j) {
            *(uint4*)(smem + X2H + t * 80 + j * 16) =
                make_uint4(hh[4 * j], hh[4 * j + 1], hh[4 * j + 2], hh[4 * j + 3]);
            *(uint4*)(smem + X2L + t * 80 + j * 16) =
                make_uint4(ll[4 * j], ll[4 * j + 1], ll[4 * j + 2], ll[4 * j + 3]);
        }
    };

    loadC(0);
    for (int dc = 0; dc < 24; ++dc) {
        __syncthreads();              // previous chunk's frag reads done
        writeC();
        __syncthreads();
        if (dc < 23) loadC(dc + 1);   // prefetch next chunk (hides HBM/L2 latency)

        s8v ah[4], al[4], bh[4], bl[4];
        #pragma unroll
        for (int i = 0; i < 4; ++i) {
            ah[i] = *(const s8v*)(smem + X1H + (i * 16 + li) * 80 + g * 16);
            al[i] = *(const s8v*)(smem + X1L + (i * 16 + li) * 80 + g * 16);
            bh[i] = *(const s8v*)(smem + X2H + (w * 64 + i * 16 + li) * 80 + g * 16);
            bl[i] = *(const s8v*)(smem + X2L + (w * 64 + i * 16 + li) * 80 + g * 16);
        }
        #pragma unroll
        for (int qb = 0; qb < 4; ++qb)
            #pragma unroll
            for (int c = 0; c < 4; ++c) {
                acc[qb][c] = __builtin_amdgcn_mfma_f32_16x16x32_bf16(ah[qb], bh[c], acc[qb][c], 0, 0, 0);
                acc[qb][c] = __builtin_amdgcn_mfma_f32_16x16x32_bf16(ah[qb], bl[c], acc[qb][c], 0, 0, 0);
                acc[qb][c] = __builtin_amdgcn_mfma_f32_16x16x32_bf16(al[qb], bh[c], acc[qb][c], 0, 0, 0);
            }
    }

    // ================= Phase 2: softmax + dropout -> P (bf16, LDS) ==========
    // kill pad column k=511 (lives at w=7, c=3, li=15)
    if (w == 7 && li == 15) {
        #pragma unroll
        for (int qb = 0; qb < 4; ++qb)
            #pragma unroll
            for (int r = 0; r < 4; ++r) acc[qb][3][r] = -3.0e38f;
    }
    // row max: in-lane over c, cross-lane over li, cross-wave via LDS
    #pragma unroll
    for (int qb = 0; qb < 4; ++qb)
        #pragma unroll
        for (int r = 0; r < 4; ++r) {
            float v = fmaxf(fmaxf(acc[qb][0][r], acc[qb][1][r]),
                            fmaxf(acc[qb][2][r], acc[qb][3][r]));
            v = fmaxf(v, __shfl_xor(v, 1));
            v = fmaxf(v, __shfl_xor(v, 2));
            v = fmaxf(v, __shfl_xor(v, 4));
            v = fmaxf(v, __shfl_xor(v, 8));
            if (li == 0) redp[(qb * 16 + g * 4 + r) * 8 + w] = v;
        }
    __syncthreads();
    if (t < 64) {
        float v = redp[t * 8];
        #pragma unroll
        for (int i = 1; i < 8; ++i) v = fmaxf(v, redp[t * 8 + i]);
        mldp[t] = v;
    }
    __syncthreads();
    // e = exp(s - m); row sum (over ALL k incl. dropped -- mask NOT applied here)
    #pragma unroll
    for (int qb = 0; qb < 4; ++qb)
        #pragma unroll
        for (int r = 0; r < 4; ++r) {
            const float m = mldp[qb * 16 + g * 4 + r];
            float e0 = __expf(acc[qb][0][r] - m);
            float e1 = __expf(acc[qb][1][r] - m);
            float e2 = __expf(acc[qb][2][r] - m);
            float e3 = __expf(acc[qb][3][r] - m);
            acc[qb][0][r] = e0; acc[qb][1][r] = e1;
            acc[qb][2][r] = e2; acc[qb][3][r] = e3;
            float s = (e0 + e1) + (e2 + e3);
            s += __shfl_xor(s, 1);
            s += __shfl_xor(s, 2);
            s += __shfl_xor(s, 4);
            s += __shfl_xor(s, 8);
            if (li == 0) redp[(qb * 16 + g * 4 + r) * 8 + w] = s;
        }
    __syncthreads();
    if (t < 64) {
        float s = redp[t * 8];
        #pragma unroll
        for (int i = 1; i < 8; ++i) s += redp[t * 8 + i];
        fldp[t] = INV_KEEP / s;
    }
    // numerator mask + pack pairs (k even in lane, partner from lane^1) -> P
    #pragma unroll
    for (int qb = 0; qb < 4; ++qb)
        #pragma unroll
        for (int c = 0; c < 4; ++c)
            #pragma unroll
            for (int r = 0; r < 4; ++r) {
                const int q = qb * 16 + g * 4 + r;
                const int k = w * 64 + c * 16 + li;
                float p = 0.f;
                if (k < NK && mb[(size_t)q * NK + k] != 0) p = acc[qb][c][r];
                float po = __shfl_xor(p, 1);
                if ((li & 1) == 0)
                    *(unsigned*)(smem + P_BASE + q * P_PITCH_B + k * 2) = pk_hi(p, po);
            }

    // ================= Phase 3: O = P @ V (V staged transposed) =============
    f32x4 o[4][6] = {};   // [qb][nf]: q = qb*16 + g*4 + r, d = 96w + 16nf + li
    float4 vv[3][4];
    auto loadVt = [&](int kc) {
        #pragma unroll
        for (int p = 0; p < 3; ++p) {
            const int bid = t + 512 * p;
            const int kb = bid & 7, db = bid >> 3;
            const float* src = x2b + (size_t)(kc * 32 + kb * 4) * ND + db * 4;
            #pragma unroll
            for (int j = 0; j < 4; ++j) {
                const int kg = kc * 32 + kb * 4 + j;
                vv[p][j] = (kg < NK) ? *(const float4*)(src + (size_t)j * ND)
                                     : make_float4(0.f, 0.f, 0.f, 0.f);  // zero pad: avoid 0*NaN
            }
        }
    };
    auto writeVt = [&]() {
        #pragma unroll
        for (int p = 0; p < 3; ++p) {
            const int bid = t + 512 * p;
            const int kb = bid & 7, db = bid >> 3;
            float4 v0 = vv[p][0], v1 = vv[p][1], v2 = vv[p][2], v3 = vv[p][3];
            char* base = smem + VT + db * 320 + kb * 8;   // row d=4db+i, pitch 80 B
            *(uint2*)(base +   0) = make_uint2(pk_hi(v0.x, v1.x), pk_hi(v2.x, v3.x));
            *(uint2*)(base +  80) = make_uint2(pk_hi(v0.y, v1.y), pk_hi(v2.y, v3.y));
            *(uint2*)(base + 160) = make_uint2(pk_hi(v0.z, v1.z), pk_hi(v2.z, v3.z));
            *(uint2*)(base + 240) = make_uint2(pk_hi(v0.w, v1.w), pk_hi(v2.w, v3.w));
        }
    };

    loadVt(0);
    for (int kc = 0; kc < 16; ++kc) {
        __syncthreads();              // prior PV frag reads done (and P writes visible at kc=0)
        writeVt();
        __syncthreads();
        if (kc < 15) loadVt(kc + 1);

        s8v pa[4], pb[6];
        #pragma unroll
        for (int qb = 0; qb < 4; ++qb)
            pa[qb] = *(const s8v*)(smem + P_BASE + (qb * 16 + li) * P_PITCH_B + (kc * 32 + g * 8) * 2);
        #pragma unroll
        for (int nf = 0; nf < 6; ++nf)
            pb[nf] = *(const s8v*)(smem + VT + (w * 96 + nf * 16 + li) * 80 + g * 16);
        #pragma unroll
        for (int qb = 0; qb < 4; ++qb)
            #pragma unroll
            for (int nf = 0; nf < 6; ++nf)
                o[qb][nf] = __builtin_amdgcn_mfma_f32_16x16x32_bf16(pa[qb], pb[nf], o[qb][nf], 0, 0, 0);
    }

    // ================= Epilogue: scale by INV_KEEP/l[q], store ==============
    #pragma unroll
    for (int qb = 0; qb < 4; ++qb)
        #pragma unroll
        for (int r = 0; r < 4; ++r) {
            const float f = fldp[qb * 16 + g * 4 + r];
            #pragma unroll
            for (int nf = 0; nf < 6; ++nf)
                ob[(size_t)(qb * 16 + g * 4 + r) * ND + w * 96 + nf * 16 + li] = o[qb][nf][r] * f;
        }
}

}  // namespace

extern "C" void kernel_launch(void* const* d_in, const int* in_sizes, int n_in,
                              void* d_out, int out_size, void* d_ws, size_t ws_size,
                              hipStream_t stream)
{
    const float* x1    = (const float*)d_in[0];
    const float* x2    = (const float*)d_in[1];
    const int*   dmask = (const int*)d_in[2];
    float*       out   = (float*)d_out;

    (void)hipFuncSetAttribute((const void*)fused_attn,
                              hipFuncAttributeMaxDynamicSharedMemorySize, LDS_TOTAL);
    fused_attn<<<dim3(NB * (NQ / TQ)), dim3(NTH), LDS_TOTAL, stream>>>(x1, x2, dmask, out);
}

// Round 5
// 286.385 us; speedup vs baseline: 3.1516x; 1.1144x over previous
//
#include <hip/hip_runtime.h>

// Fused attention, MFMA + pipelined staging.
//   scores = x1 @ x2^T (bf16 hi/lo split, 3 MFMA passes), softmax over k
//   (denominator over ALL k; pad col 511 killed), dropout on numerator,
//   out = P @ x2 (bf16). B=32 Q=512 K=511 D=768 fp32.
// R5: T14 reg-staged pipeline (raw barriers, no vmcnt drain in loop),
//     frag-major LDS (linear lane*16 ds_read_b128, conflict-free),
//     XCD-aware block swizzle (batch -> one XCD's L2).

namespace {

constexpr int NB = 32, NQ = 512, NK = 511, ND = 768;
constexpr int TQ = 64, NTH = 512;
constexpr int NCH = 24;   // phase-1 d-chunks of 32
constexpr int NKC = 16;   // phase-3 k-chunks of 32
constexpr float INV_KEEP = 1.0f / 0.9f;

// LDS byte offsets. Phase-1 staging [0,72K) is dead before P [0,64K) is written.
constexpr int X1H_OFF = 0;        // 4 qb-blocks x 1KB
constexpr int X1L_OFF = 4096;
constexpr int X2H_OFF = 8192;     // 32 blocks x 1KB
constexpr int X2L_OFF = 40960;
constexpr int P_OFF   = 0;        // 4 qb x 16 kblk x 1KB = 64KB
constexpr int VT_OFF  = 65536;    // 48 blocks x 1KB
constexpr int RED_OFF = 114688;   // 64*8 f32
constexpr int MLD_OFF = RED_OFF + 2048;
constexpr int FLD_OFF = MLD_OFF + 256;
constexpr int LDS_TOTAL = FLD_OFF + 256;   // 117248 B

typedef short s8v  __attribute__((ext_vector_type(8)));
typedef float f32x4 __attribute__((ext_vector_type(4)));

__device__ __forceinline__ unsigned f2bf(float x) {
    unsigned u = __float_as_uint(x);
    return (u + 0x7FFFu + ((u >> 16) & 1u)) >> 16;
}
__device__ __forceinline__ unsigned pk_hi(float a, float b) {
    return f2bf(a) | (f2bf(b) << 16);
}
__device__ __forceinline__ void split2(float a, float b, unsigned& hi, unsigned& lo) {
    unsigned ha = f2bf(a), hb = f2bf(b);
    float ra = a - __uint_as_float(ha << 16);
    float rb = b - __uint_as_float(hb << 16);
    hi = ha | (hb << 16);
    lo = (__float_as_uint(ra) >> 16) | ((__float_as_uint(rb) >> 16) << 16);
}

#define SCHED0() __builtin_amdgcn_sched_barrier(0)
#define BAR()    __builtin_amdgcn_s_barrier()
#define LGKM0()  asm volatile("s_waitcnt lgkmcnt(0)" ::: "memory")

__global__ __launch_bounds__(NTH, 2)
void fused_attn(const float* __restrict__ x1, const float* __restrict__ x2,
                const int* __restrict__ dmask, float* __restrict__ out)
{
    extern __shared__ char smem[];
    const int t  = threadIdx.x;
    const int w  = t >> 6;     // wave 0..7
    const int l  = t & 63;     // lane
    const int li = l & 15;
    const int g  = l >> 4;

    // XCD swizzle: blocks bid%8==x run on XCD x; give each XCD 4 whole batches.
    const int logical = ((blockIdx.x & 7) << 5) | (blockIdx.x >> 3);
    const int b  = logical >> 3;
    const int q0 = (logical & 7) * TQ;

    const float* x1b = x1 + (size_t)(b * NQ + q0) * ND;
    const float* x2b = x2 + (size_t)b * NK * ND;
    const int*   mb  = dmask + (size_t)(b * NQ + q0) * NK;
    float*       ob  = out + (size_t)(b * NQ + q0) * ND;

    float* redp = (float*)(smem + RED_OFF);
    float* mldp = (float*)(smem + MLD_OFF);
    float* fldp = (float*)(smem + FLD_OFF);

    // ===== Phase 1: S[64][512] = x1 @ x2^T, bf16 hi/lo split ================
    f32x4 acc[4][4] = {};   // [qb][c]: q = qb*16+g*4+r, k = 64w+16c+li

    f32x4 px1;              // x1: row t>>3, float4 col-group t&7
    f32x4 pxa[4], pxb[4];   // x2: task j: row (t>>2)+128j, col-octet t&3
    const int r0 = t >> 2, gq1 = t & 3;

    auto loadStage = [&](int dc) {
        const int d0 = dc * 32;
        px1 = *(const f32x4*)(x1b + (size_t)(t >> 3) * ND + d0 + (t & 7) * 4);
        #pragma unroll
        for (int j = 0; j < 4; ++j) {
            const int r = r0 + 128 * j;
            if (r < NK) {
                pxa[j] = *(const f32x4*)(x2b + (size_t)r * ND + d0 + gq1 * 8);
                pxb[j] = *(const f32x4*)(x2b + (size_t)r * ND + d0 + gq1 * 8 + 4);
            } else {
                pxa[j] = (f32x4){0.f, 0.f, 0.f, 0.f};
                pxb[j] = (f32x4){0.f, 0.f, 0.f, 0.f};
            }
        }
    };
    auto writeStage = [&]() {
        {   // x1: half-slot (8B) per thread, frag-major: blk=q>>4, slot=(cg>>1)*16+(q&15)
            unsigned h0, l0_, h1, l1_;
            split2(px1[0], px1[1], h0, l0_);
            split2(px1[2], px1[3], h1, l1_);
            const int q = t >> 3, cg = t & 7;
            const int a = (q >> 4) * 1024 + ((cg >> 1) * 16 + (q & 15)) * 16 + (cg & 1) * 8;
            *(uint2*)(smem + X1H_OFF + a) = make_uint2(h0, h1);
            *(uint2*)(smem + X1L_OFF + a) = make_uint2(l0_, l1_);
        }
        #pragma unroll
        for (int j = 0; j < 4; ++j) {   // x2: one 16B slot (8 bf16) per task
            const int r = r0 + 128 * j;
            unsigned hh[4], ll[4];
            split2(pxa[j][0], pxa[j][1], hh[0], ll[0]);
            split2(pxa[j][2], pxa[j][3], hh[1], ll[1]);
            split2(pxb[j][0], pxb[j][1], hh[2], ll[2]);
            split2(pxb[j][2], pxb[j][3], hh[3], ll[3]);
            const int a = (r >> 4) * 1024 + (gq1 * 16 + (r & 15)) * 16;
            *(uint4*)(smem + X2H_OFF + a) = make_uint4(hh[0], hh[1], hh[2], hh[3]);
            *(uint4*)(smem + X2L_OFF + a) = make_uint4(ll[0], ll[1], ll[2], ll[3]);
        }
    };

    loadStage(0);
    for (int dc = 0; dc < NCH; ++dc) {
        SCHED0(); BAR(); SCHED0();          // buf free (prev frag reads consumed pre-MFMA)
        writeStage();
        if (dc + 1 < NCH) loadStage(dc + 1);  // global loads fly under MFMA below
        LGKM0(); SCHED0(); BAR(); SCHED0(); // buf ready

        s8v ah[4], al[4], bh[4], bl[4];
        #pragma unroll
        for (int i = 0; i < 4; ++i) {       // all reads: base + lane*16 (conflict-free)
            ah[i] = *(const s8v*)(smem + X1H_OFF + i * 1024 + l * 16);
            al[i] = *(const s8v*)(smem + X1L_OFF + i * 1024 + l * 16);
            bh[i] = *(const s8v*)(smem + X2H_OFF + (w * 4 + i) * 1024 + l * 16);
            bl[i] = *(const s8v*)(smem + X2L_OFF + (w * 4 + i) * 1024 + l * 16);
        }
        #pragma unroll
        for (int qb = 0; qb < 4; ++qb)
            #pragma unroll
            for (int c = 0; c < 4; ++c) {
                acc[qb][c] = __builtin_amdgcn_mfma_f32_16x16x32_bf16(ah[qb], bh[c], acc[qb][c], 0, 0, 0);
                acc[qb][c] = __builtin_amdgcn_mfma_f32_16x16x32_bf16(ah[qb], bl[c], acc[qb][c], 0, 0, 0);
                acc[qb][c] = __builtin_amdgcn_mfma_f32_16x16x32_bf16(al[qb], bh[c], acc[qb][c], 0, 0, 0);
            }
    }
    __syncthreads();

    // ===== Phase 2: softmax + dropout -> P (bf16, frag-major LDS) ===========
    if (w == 7 && li == 15) {   // kill pad column k=511
        #pragma unroll
        for (int qb = 0; qb < 4; ++qb)
            #pragma unroll
            for (int r = 0; r < 4; ++r) acc[qb][3][r] = -3.0e38f;
    }
    #pragma unroll
    for (int qb = 0; qb < 4; ++qb)
        #pragma unroll
        for (int r = 0; r < 4; ++r) {
            float v = fmaxf(fmaxf(acc[qb][0][r], acc[qb][1][r]),
                            fmaxf(acc[qb][2][r], acc[qb][3][r]));
            v = fmaxf(v, __shfl_xor(v, 1));
            v = fmaxf(v, __shfl_xor(v, 2));
            v = fmaxf(v, __shfl_xor(v, 4));
            v = fmaxf(v, __shfl_xor(v, 8));
            if (li == 0) redp[(qb * 16 + g * 4 + r) * 8 + w] = v;
        }
    __syncthreads();
    if (t < 64) {
        float v = redp[t * 8];
        #pragma unroll
        for (int i = 1; i < 8; ++i) v = fmaxf(v, redp[t * 8 + i]);
        mldp[t] = v;
    }
    __syncthreads();
    #pragma unroll
    for (int qb = 0; qb < 4; ++qb)
        #pragma unroll
        for (int r = 0; r < 4; ++r) {
            const float m = mldp[qb * 16 + g * 4 + r];
            float e0 = __expf(acc[qb][0][r] - m);
            float e1 = __expf(acc[qb][1][r] - m);
            float e2 = __expf(acc[qb][2][r] - m);
            float e3 = __expf(acc[qb][3][r] - m);
            acc[qb][0][r] = e0; acc[qb][1][r] = e1;
            acc[qb][2][r] = e2; acc[qb][3][r] = e3;
            float s = (e0 + e1) + (e2 + e3);
            s += __shfl_xor(s, 1);
            s += __shfl_xor(s, 2);
            s += __shfl_xor(s, 4);
            s += __shfl_xor(s, 8);
            if (li == 0) redp[(qb * 16 + g * 4 + r) * 8 + w] = s;
        }
    __syncthreads();
    if (t < 64) {
        float s = redp[t * 8];
        #pragma unroll
        for (int i = 1; i < 8; ++i) s += redp[t * 8 + i];
        fldp[t] = INV_KEEP / s;   // denominator over ALL k (mask not applied)
    }
    // numerator mask; pack bf16 pairs into frag-major P
    #pragma unroll
    for (int qb = 0; qb < 4; ++qb)
        #pragma unroll
        for (int c = 0; c < 4; ++c)
            #pragma unroll
            for (int r = 0; r < 4; ++r) {
                const int q = qb * 16 + g * 4 + r;
                const int k = w * 64 + c * 16 + li;
                float p = 0.f;
                if (k < NK && mb[(size_t)q * NK + k] != 0) p = acc[qb][c][r];
                float po = __shfl_xor(p, 1);
                if ((li & 1) == 0)
                    *(unsigned*)(smem + P_OFF + qb * 16384 + (k >> 5) * 1024 +
                                 ((k >> 3) & 3) * 256 + (q & 15) * 16 + (k & 7) * 2) = pk_hi(p, po);
            }

    // ===== Phase 3: O = P @ V, V transposed into frag-major LDS =============
    f32x4 o[4][6] = {};   // [qb][nf]: q = qb*16+g*4+r, d = 96w+16nf+li
    f32x4 va[8], vb[8];   // task A: all threads; task B: t<256
    const int dqA = t >> 2, gqA = t & 3;
    const int dqB = 128 + (t >> 2);

    auto loadV = [&](int kc) {
        const int kbase = kc * 32;
        #pragma unroll
        for (int e = 0; e < 8; ++e) {
            const int k = kbase + gqA * 8 + e;
            va[e] = (k < NK) ? *(const f32x4*)(x2b + (size_t)k * ND + dqA * 4)
                             : (f32x4){0.f, 0.f, 0.f, 0.f};
        }
        if (t < 256) {
            #pragma unroll
            for (int e = 0; e < 8; ++e) {
                const int k = kbase + gqA * 8 + e;
                vb[e] = (k < NK) ? *(const f32x4*)(x2b + (size_t)k * ND + dqB * 4)
                                 : (f32x4){0.f, 0.f, 0.f, 0.f};
            }
        }
    };
    auto writeV = [&]() {
        #pragma unroll
        for (int c = 0; c < 4; ++c) {
            const int d = dqA * 4 + c;
            const int wp = d / 96, rem = d - wp * 96;
            const int a = VT_OFF + (wp * 6 + (rem >> 4)) * 1024 + gqA * 256 + ((d & 15) ^ gqA) * 16;
            *(uint4*)(smem + a) = make_uint4(pk_hi(va[0][c], va[1][c]), pk_hi(va[2][c], va[3][c]),
                                             pk_hi(va[4][c], va[5][c]), pk_hi(va[6][c], va[7][c]));
        }
        if (t < 256) {
            #pragma unroll
            for (int c = 0; c < 4; ++c) {
                const int d = dqB * 4 + c;
                const int wp = d / 96, rem = d - wp * 96;
                const int a = VT_OFF + (wp * 6 + (rem >> 4)) * 1024 + gqA * 256 + ((d & 15) ^ gqA) * 16;
                *(uint4*)(smem + a) = make_uint4(pk_hi(vb[0][c], vb[1][c]), pk_hi(vb[2][c], vb[3][c]),
                                                 pk_hi(vb[4][c], vb[5][c]), pk_hi(vb[6][c], vb[7][c]));
            }
        }
    };

    loadV(0);
    __syncthreads();   // P visible to all waves
    for (int kc = 0; kc < NKC; ++kc) {
        SCHED0(); BAR(); SCHED0();
        writeV();
        if (kc + 1 < NKC) loadV(kc + 1);
        LGKM0(); SCHED0(); BAR(); SCHED0();

        s8v pa[4], pb[6];
        #pragma unroll
        for (int qb = 0; qb < 4; ++qb)
            pa[qb] = *(const s8v*)(smem + P_OFF + qb * 16384 + kc * 1024 + l * 16);
        #pragma unroll
        for (int nf = 0; nf < 6; ++nf)
            pb[nf] = *(const s8v*)(smem + VT_OFF + (w * 6 + nf) * 1024 + g * 256 + (li ^ g) * 16);
        #pragma unroll
        for (int qb = 0; qb < 4; ++qb)
            #pragma unroll
            for (int nf = 0; nf < 6; ++nf)
                o[qb][nf] = __builtin_amdgcn_mfma_f32_16x16x32_bf16(pa[qb], pb[nf], o[qb][nf], 0, 0, 0);
    }

    // ===== Epilogue =========================================================
    #pragma unroll
    for (int qb = 0; qb < 4; ++qb)
        #pragma unroll
        for (int r = 0; r < 4; ++r) {
            const float f = fldp[qb * 16 + g * 4 + r];
            #pragma unroll
            for (int nf = 0; nf < 6; ++nf)
                ob[(size_t)(qb * 16 + g * 4 + r) * ND + w * 96 + nf * 16 + li] = o[qb][nf][r] * f;
        }
}

}  // namespace

extern "C" void kernel_launch(void* const* d_in, const int* in_sizes, int n_in,
                              void* d_out, int out_size, void* d_ws, size_t ws_size,
                              hipStream_t stream)
{
    const float* x1    = (const float*)d_in[0];
    const float* x2    = (const float*)d_in[1];
    const int*   dmask = (const int*)d_in[2];
    float*       out   = (float*)d_out;

    (void)hipFuncSetAttribute((const void*)fused_attn,
                              hipFuncAttributeMaxDynamicSharedMemorySize, LDS_TOTAL);
    fused_attn<<<dim3(NB * (NQ / TQ)), dim3(NTH), LDS_TOTAL, stream>>>(x1, x2, dmask, out);
}

// Round 6
// 278.496 us; speedup vs baseline: 3.2409x; 1.0283x over previous
//
#include <hip/hip_runtime.h>

// Fused attention, MFMA + true double-buffered pipelines (R6).
//   scores = x1 @ x2^T (bf16 hi/lo split, 3 MFMA passes), softmax over k
//   (denominator over ALL k; pad col 511 killed), dropout on numerator,
//   out = P @ x2 (bf16). B=32 Q=512 K=511 D=768 fp32.
// One barrier per pipeline iteration; staging conversion + global prefetch
// run under MFMA of the other buffer. LDS: phase1 dbuf 2x72K; P 64K aliases
// buf0; phase3 Vt dbuf 2x48K aliases buf1; softmax scratch inside VT1.

namespace {

constexpr int NB = 32, NQ = 512, NK = 511, ND = 768;
constexpr int TQ = 64, NTH = 512;
constexpr int NCH = 24;   // phase-1 d-chunks of 32
constexpr int NKC = 16;   // phase-3 k-chunks of 32
constexpr float INV_KEEP = 1.0f / 0.9f;

// ---- LDS map (bytes) ----
constexpr int BUF0   = 0;        // phase-1 staging buffer 0 (72K)
constexpr int BUF1   = 73728;    // phase-1 staging buffer 1 (72K) [73728,147456)
constexpr int X1H_O  = 0;        // within buf: 4K
constexpr int X1L_O  = 4096;     // 4K
constexpr int X2H_O  = 8192;     // 32K
constexpr int X2L_O  = 40960;    // 32K
constexpr int P_OFF  = 0;        // P bf16 frag-major, 64K (after phase 1)
constexpr int VT0    = 65536;    // Vt buffer 0, 48K
constexpr int VT1    = 114688;   // Vt buffer 1, 48K [114688,163840)
constexpr int RED_OFF = 150528;  // scratch (inside VT1, phase-2 only)
constexpr int MLD_OFF = RED_OFF + 2048;
constexpr int FLD_OFF = MLD_OFF + 256;
constexpr int LDS_TOTAL = 163840;   // exactly 160 KiB

typedef short s8v   __attribute__((ext_vector_type(8)));
typedef float f32x4 __attribute__((ext_vector_type(4)));

__device__ __forceinline__ unsigned f2bf(float x) {
    unsigned u = __float_as_uint(x);
    return (u + 0x7FFFu + ((u >> 16) & 1u)) >> 16;
}
__device__ __forceinline__ unsigned pk_hi(float a, float b) {
    return f2bf(a) | (f2bf(b) << 16);
}
__device__ __forceinline__ void split2(float a, float b, unsigned& hi, unsigned& lo) {
    unsigned ha = f2bf(a), hb = f2bf(b);
    float ra = a - __uint_as_float(ha << 16);
    float rb = b - __uint_as_float(hb << 16);
    hi = ha | (hb << 16);
    lo = (__float_as_uint(ra) >> 16) | ((__float_as_uint(rb) >> 16) << 16);
}

__global__ __launch_bounds__(NTH, 2)
void fused_attn(const float* __restrict__ x1, const float* __restrict__ x2,
                const int* __restrict__ dmask, float* __restrict__ out)
{
    extern __shared__ char smem[];
    const int t  = threadIdx.x;
    const int w  = t >> 6;     // wave 0..7
    const int l  = t & 63;
    const int li = l & 15;
    const int g  = l >> 4;

    // XCD swizzle: 4 whole batches per XCD -> x2/x1 re-reads L2-hit
    const int logical = ((blockIdx.x & 7) << 5) | (blockIdx.x >> 3);
    const int b  = logical >> 3;
    const int q0 = (logical & 7) * TQ;

    const float* x1b = x1 + (size_t)(b * NQ + q0) * ND;
    const float* x2b = x2 + (size_t)b * NK * ND;
    const int*   mb  = dmask + (size_t)(b * NQ + q0) * NK;
    float*       ob  = out + (size_t)(b * NQ + q0) * ND;

    float* redp = (float*)(smem + RED_OFF);
    float* mldp = (float*)(smem + MLD_OFF);
    float* fldp = (float*)(smem + FLD_OFF);

    // ===== Phase 1: S[64][512] = x1 @ x2^T, bf16 hi/lo split ================
    f32x4 acc[4][4] = {};   // [qb][c]: q = qb*16+g*4+r, k = 64w+16c+li

    f32x4 px1;              // x1: row t>>3, float4 col-group t&7
    f32x4 pxa[4], pxb[4];   // x2: task j: row (t>>2)+128j, col pair at (t&3)*8
    const int r0 = t >> 2, gq1 = t & 3;

    auto loadStage = [&](int dc) {
        const int d0 = dc * 32;
        px1 = *(const f32x4*)(x1b + (size_t)(t >> 3) * ND + d0 + (t & 7) * 4);
        #pragma unroll
        for (int j = 0; j < 4; ++j) {
            const int r = r0 + 128 * j;
            if (r < NK) {
                pxa[j] = *(const f32x4*)(x2b + (size_t)r * ND + d0 + gq1 * 8);
                pxb[j] = *(const f32x4*)(x2b + (size_t)r * ND + d0 + gq1 * 8 + 4);
            } else {
                pxa[j] = (f32x4){0.f, 0.f, 0.f, 0.f};
                pxb[j] = (f32x4){0.f, 0.f, 0.f, 0.f};
            }
        }
    };
    auto writeStage = [&](char* bb) {
        {   // x1: 8B half-slot per thread, frag-major
            unsigned h0, l0_, h1, l1_;
            split2(px1[0], px1[1], h0, l0_);
            split2(px1[2], px1[3], h1, l1_);
            const int q = t >> 3, cg = t & 7;
            const int a = (q >> 4) * 1024 + ((cg >> 1) * 16 + (q & 15)) * 16 + (cg & 1) * 8;
            *(uint2*)(bb + X1H_O + a) = make_uint2(h0, h1);
            *(uint2*)(bb + X1L_O + a) = make_uint2(l0_, l1_);
        }
        #pragma unroll
        for (int j = 0; j < 4; ++j) {   // x2: one full 16B slot per task
            const int r = r0 + 128 * j;
            unsigned hh[4], ll[4];
            split2(pxa[j][0], pxa[j][1], hh[0], ll[0]);
            split2(pxa[j][2], pxa[j][3], hh[1], ll[1]);
            split2(pxb[j][0], pxb[j][1], hh[2], ll[2]);
            split2(pxb[j][2], pxb[j][3], hh[3], ll[3]);
            const int a = (r >> 4) * 1024 + (gq1 * 16 + (r & 15)) * 16;
            *(uint4*)(bb + X2H_O + a) = make_uint4(hh[0], hh[1], hh[2], hh[3]);
            *(uint4*)(bb + X2L_O + a) = make_uint4(ll[0], ll[1], ll[2], ll[3]);
        }
    };

    // prologue: fill buf0, prefetch chunk 1
    loadStage(0);
    writeStage(smem + BUF0);
    loadStage(1);
    __syncthreads();

    for (int dc = 0; dc < NCH; ++dc) {
        char* cb = smem + ((dc & 1) ? BUF1 : BUF0);
        char* nb = smem + ((dc & 1) ? BUF0 : BUF1);
        if (dc + 1 < NCH) writeStage(nb);          // convert+stage next (regs from dc+1 load)
        if (dc + 2 < NCH) loadStage(dc + 2);       // issue globals 2 chunks ahead

        s8v ah[4], al[4], bh[4], bl[4];
        #pragma unroll
        for (int i = 0; i < 4; ++i) {              // base + lane*16: conflict-free
            ah[i] = *(const s8v*)(cb + X1H_O + i * 1024 + l * 16);
            al[i] = *(const s8v*)(cb + X1L_O + i * 1024 + l * 16);
            bh[i] = *(const s8v*)(cb + X2H_O + (w * 4 + i) * 1024 + l * 16);
            bl[i] = *(const s8v*)(cb + X2L_O + (w * 4 + i) * 1024 + l * 16);
        }
        #pragma unroll
        for (int qb = 0; qb < 4; ++qb)
            #pragma unroll
            for (int c = 0; c < 4; ++c) {
                acc[qb][c] = __builtin_amdgcn_mfma_f32_16x16x32_bf16(ah[qb], bh[c], acc[qb][c], 0, 0, 0);
                acc[qb][c] = __builtin_amdgcn_mfma_f32_16x16x32_bf16(ah[qb], bl[c], acc[qb][c], 0, 0, 0);
                acc[qb][c] = __builtin_amdgcn_mfma_f32_16x16x32_bf16(al[qb], bh[c], acc[qb][c], 0, 0, 0);
            }
        __syncthreads();   // nb ready for next iter; cb reads done before re-write
    }

    // ===== Phase 2: softmax + dropout -> P (bf16, frag-major LDS) ===========
    if (w == 7 && li == 15) {   // kill pad column k=511
        #pragma unroll
        for (int qb = 0; qb < 4; ++qb)
            #pragma unroll
            for (int r = 0; r < 4; ++r) acc[qb][3][r] = -3.0e38f;
    }
    #pragma unroll
    for (int qb = 0; qb < 4; ++qb)
        #pragma unroll
        for (int r = 0; r < 4; ++r) {
            float v = fmaxf(fmaxf(acc[qb][0][r], acc[qb][1][r]),
                            fmaxf(acc[qb][2][r], acc[qb][3][r]));
            v = fmaxf(v, __shfl_xor(v, 1));
            v = fmaxf(v, __shfl_xor(v, 2));
            v = fmaxf(v, __shfl_xor(v, 4));
            v = fmaxf(v, __shfl_xor(v, 8));
            if (li == 0) redp[(qb * 16 + g * 4 + r) * 8 + w] = v;
        }
    __syncthreads();
    if (t < 64) {
        float v = redp[t * 8];
        #pragma unroll
        for (int i = 1; i < 8; ++i) v = fmaxf(v, redp[t * 8 + i]);
        mldp[t] = v;
    }
    __syncthreads();
    #pragma unroll
    for (int qb = 0; qb < 4; ++qb)
        #pragma unroll
        for (int r = 0; r < 4; ++r) {
            const float m = mldp[qb * 16 + g * 4 + r];
            float e0 = __expf(acc[qb][0][r] - m);
            float e1 = __expf(acc[qb][1][r] - m);
            float e2 = __expf(acc[qb][2][r] - m);
            float e3 = __expf(acc[qb][3][r] - m);
            acc[qb][0][r] = e0; acc[qb][1][r] = e1;
            acc[qb][2][r] = e2; acc[qb][3][r] = e3;
            float s = (e0 + e1) + (e2 + e3);
            s += __shfl_xor(s, 1);
            s += __shfl_xor(s, 2);
            s += __shfl_xor(s, 4);
            s += __shfl_xor(s, 8);
            if (li == 0) redp[(qb * 16 + g * 4 + r) * 8 + w] = s;
        }
    __syncthreads();
    if (t < 64) {
        float s = redp[t * 8];
        #pragma unroll
        for (int i = 1; i < 8; ++i) s += redp[t * 8 + i];
        fldp[t] = INV_KEEP / s;   // denominator over ALL k (mask not applied)
    }
    __syncthreads();

    // hoist 1/l into regs BEFORE Vt clobbers the scratch region
    float fr[4][4];
    #pragma unroll
    for (int qb = 0; qb < 4; ++qb)
        #pragma unroll
        for (int r = 0; r < 4; ++r) fr[qb][r] = fldp[qb * 16 + g * 4 + r];

    // numerator mask; pack bf16 pairs into frag-major P
    #pragma unroll
    for (int qb = 0; qb < 4; ++qb)
        #pragma unroll
        for (int c = 0; c < 4; ++c)
            #pragma unroll
            for (int r = 0; r < 4; ++r) {
                const int q = qb * 16 + g * 4 + r;
                const int k = w * 64 + c * 16 + li;
                float p = 0.f;
                if (k < NK && mb[(size_t)q * NK + k] != 0) p = acc[qb][c][r];
                float po = __shfl_xor(p, 1);
                if ((li & 1) == 0)
                    *(unsigned*)(smem + P_OFF + qb * 16384 + (k >> 5) * 1024 +
                                 ((k >> 3) & 3) * 256 + (q & 15) * 16 + (k & 7) * 2) = pk_hi(p, po);
            }

    // ===== Phase 3: O = P @ V, V transposed into frag-major LDS (dbuf) ======
    f32x4 o[4][6] = {};   // [qb][nf]: q = qb*16+g*4+r, d = 96w+16nf+li
    f32x4 va[8], vb[8];
    const int dqA = t >> 2, gqA = t & 3;
    const int dqB = 128 + (t >> 2);

    auto loadV = [&](int kc) {
        const int kbase = kc * 32;
        #pragma unroll
        for (int e = 0; e < 8; ++e) {
            const int k = kbase + gqA * 8 + e;
            va[e] = (k < NK) ? *(const f32x4*)(x2b + (size_t)k * ND + dqA * 4)
                             : (f32x4){0.f, 0.f, 0.f, 0.f};
        }
        if (t < 256) {
            #pragma unroll
            for (int e = 0; e < 8; ++e) {
                const int k = kbase + gqA * 8 + e;
                vb[e] = (k < NK) ? *(const f32x4*)(x2b + (size_t)k * ND + dqB * 4)
                                 : (f32x4){0.f, 0.f, 0.f, 0.f};
            }
        }
    };
    auto writeV = [&](char* vbase) {
        #pragma unroll
        for (int c = 0; c < 4; ++c) {
            const int d = dqA * 4 + c;
            const int wp = d / 96, rem = d - wp * 96;
            const int a = (wp * 6 + (rem >> 4)) * 1024 + gqA * 256 + ((d & 15) ^ gqA) * 16;
            *(uint4*)(vbase + a) = make_uint4(pk_hi(va[0][c], va[1][c]), pk_hi(va[2][c], va[3][c]),
                                              pk_hi(va[4][c], va[5][c]), pk_hi(va[6][c], va[7][c]));
        }
        if (t < 256) {
            #pragma unroll
            for (int c = 0; c < 4; ++c) {
                const int d = dqB * 4 + c;
                const int wp = d / 96, rem = d - wp * 96;
                const int a = (wp * 6 + (rem >> 4)) * 1024 + gqA * 256 + ((d & 15) ^ gqA) * 16;
                *(uint4*)(vbase + a) = make_uint4(pk_hi(vb[0][c], vb[1][c]), pk_hi(vb[2][c], vb[3][c]),
                                                  pk_hi(vb[4][c], vb[5][c]), pk_hi(vb[6][c], vb[7][c]));
            }
        }
    };

    // prologue: fill VT0, prefetch chunk 1
    loadV(0);
    writeV(smem + VT0);
    loadV(1);
    __syncthreads();   // VT0 ready + P visible to all waves

    for (int kc = 0; kc < NKC; ++kc) {
        char* cv = smem + ((kc & 1) ? VT1 : VT0);
        char* nv = smem + ((kc & 1) ? VT0 : VT1);
        if (kc + 1 < NKC) writeV(nv);
        if (kc + 2 < NKC) loadV(kc + 2);

        s8v pa[4], pb[6];
        #pragma unroll
        for (int qb = 0; qb < 4; ++qb)
            pa[qb] = *(const s8v*)(smem + P_OFF + qb * 16384 + kc * 1024 + l * 16);
        #pragma unroll
        for (int nf = 0; nf < 6; ++nf)
            pb[nf] = *(const s8v*)(cv + (w * 6 + nf) * 1024 + g * 256 + (li ^ g) * 16);
        #pragma unroll
        for (int qb = 0; qb < 4; ++qb)
            #pragma unroll
            for (int nf = 0; nf < 6; ++nf)
                o[qb][nf] = __builtin_amdgcn_mfma_f32_16x16x32_bf16(pa[qb], pb[nf], o[qb][nf], 0, 0, 0);
        __syncthreads();
    }

    // ===== Epilogue =========================================================
    #pragma unroll
    for (int qb = 0; qb < 4; ++qb)
        #pragma unroll
        for (int r = 0; r < 4; ++r) {
            const float f = fr[qb][r];
            #pragma unroll
            for (int nf = 0; nf < 6; ++nf)
                ob[(size_t)(qb * 16 + g * 4 + r) * ND + w * 96 + nf * 16 + li] = o[qb][nf][r] * f;
        }
}

}  // namespace

extern "C" void kernel_launch(void* const* d_in, const int* in_sizes, int n_in,
                              void* d_out, int out_size, void* d_ws, size_t ws_size,
                              hipStream_t stream)
{
    const float* x1    = (const float*)d_in[0];
    const float* x2    = (const float*)d_in[1];
    const int*   dmask = (const int*)d_in[2];
    float*       out   = (float*)d_out;

    (void)hipFuncSetAttribute((const void*)fused_attn,
                              hipFuncAttributeMaxDynamicSharedMemorySize, LDS_TOTAL);
    fused_attn<<<dim3(NB * (NQ / TQ)), dim3(NTH), LDS_TOTAL, stream>>>(x1, x2, dmask, out);
}